// Round 5
// baseline (313.790 us; speedup 1.0000x reference)
//
#include <hip/hip_runtime.h>
#include <stdint.h>

#define DI __device__ __forceinline__

typedef __attribute__((ext_vector_type(8))) __bf16 bf16x8;
typedef __attribute__((ext_vector_type(8))) unsigned short u16x8;
typedef __attribute__((ext_vector_type(4))) float f32x4;
typedef __attribute__((ext_vector_type(4))) uint32_t u32x4;
typedef unsigned short u16;

constexpr int Bb = 4, Cc = 256, Ss = 4096, HD = 64;
constexpr int ELEMS = Bb * Cc * Ss;  // 4194304

DI u16 f2bf(float f) {  // RNE
  union { float f; unsigned u; } x; x.f = f;
  return (u16)((x.u + 0x7FFFu + ((x.u >> 16) & 1u)) >> 16);
}
DI uint32_t pack2bf(float a, float b) {  // low16=bf(a), high16=bf(b)
  union { float f; uint32_t u; } xa, xb;
  xa.f = a; xb.f = b;
  return __builtin_amdgcn_perm(xb.u + 0x8000u, xa.u + 0x8000u, 0x07060302u);
}
DI bf16x8 ldfrag(const u16* p) { return __builtin_bit_cast(bf16x8, *(const u16x8*)p); }

// ---------------- fp32 -> bf16 convert ----------------
__global__ __launch_bounds__(256) void k_conv(const float* __restrict__ src, u16* __restrict__ dst, int n) {
  int i = blockIdx.x * 256 + threadIdx.x;
  if (i < n) dst[i] = f2bf(src[i]);
}

// ---------------- kernel 0: x (B,C,S) fp32 -> xt (B,S,C) bf16 ----------------
__global__ __launch_bounds__(256) void k_transpose(const float* __restrict__ x, u16* __restrict__ xt) {
  __shared__ u16 T[64][72];
  const int st = blockIdx.x, ct = blockIdx.y, b = blockIdx.z;
  const int tid = threadIdx.x;
#pragma unroll
  for (int e = 0; e < 2; e++) {
    int ss = tid + e * 256;
    int r = ss >> 3, seg = ss & 7;
    size_t base = ((size_t)(b * Cc + ct * 64 + r) << 12) + st * 64 + seg * 8;
    u16x8 t;
#pragma unroll
    for (int j = 0; j < 8; j++) t[j] = f2bf(x[base + j]);
    *(u16x8*)&T[r][seg * 8] = t;
  }
  __syncthreads();
#pragma unroll
  for (int e = 0; e < 2; e++) {
    int ss = tid + e * 256;
    int sr = ss >> 3, cseg = ss & 7;
    u16x8 o;
#pragma unroll
    for (int j = 0; j < 8; j++) o[j] = T[cseg * 8 + j][sr];
    *(u16x8*)(xt + ((size_t)(b * Ss + st * 64 + sr) << 8) + ct * 64 + cseg * 8) = o;
  }
}

// ---- shared GEMM staging: rows [r0,r0+128) x cols [k0,k0+32), pitch-40 LDS ----
DI void stage_tile(const u16* __restrict__ src, int pitch, int r0, int k0, u16 (*dst)[40], int tid) {
#pragma unroll
  for (int e = 0; e < 2; e++) {
    int c = tid + e * 256;
    int row = c >> 2, seg = c & 3;
    u16x8 t = *(const u16x8*)(src + (size_t)(r0 + row) * pitch + k0 + seg * 8);
    *(u16x8*)&dst[row][seg * 8] = t;
  }
}

// ---------------- kernel 1: qkv GEMM.  q:[bh][s][64]*(0.125*log2e)  k:[bh][s][64]  v:[bh][64][perm(s)] ----------------
__global__ __launch_bounds__(256) void k_qkv(const u16* __restrict__ xt, const u16* __restrict__ w,
                                             const float* __restrict__ bias,
                                             u16* __restrict__ q, u16* __restrict__ kk_, u16* __restrict__ vt_) {
  __shared__ u16 As[128][40], Bs[128][40];
  const int tid = threadIdx.x;
  const int wv = tid >> 6, lane = tid & 63;
  const int wm = wv >> 1, wn = wv & 1;
  const int lr = lane & 15, quad = lane >> 4;
  const int r0 = blockIdx.x * 128;  // rows = b*s
  const int j0 = blockIdx.y * 128;  // cols in [0,768)
  f32x4 acc[4][4] = {};
  for (int k0 = 0; k0 < 256; k0 += 32) {
    __syncthreads();
    stage_tile(xt, 256, r0, k0, As, tid);
    stage_tile(w, 256, j0, k0, Bs, tid);
    __syncthreads();
    bf16x8 a[4], b[4];
#pragma unroll
    for (int mt = 0; mt < 4; mt++) a[mt] = ldfrag(&As[wm * 64 + mt * 16 + lr][quad * 8]);
#pragma unroll
    for (int nt = 0; nt < 4; nt++) b[nt] = ldfrag(&Bs[wn * 64 + nt * 16 + lr][quad * 8]);
#pragma unroll
    for (int mt = 0; mt < 4; mt++)
#pragma unroll
      for (int nt = 0; nt < 4; nt++)
        acc[mt][nt] = __builtin_amdgcn_mfma_f32_16x16x32_bf16(a[mt], b[nt], acc[mt][nt], 0, 0, 0);
  }
#pragma unroll
  for (int nt = 0; nt < 4; nt++) {
    int j = j0 + wn * 64 + nt * 16 + lr;
    float bj = bias[j];
    int part = j >> 8, cc = j & 255, head = cc >> 6, d = cc & 63;
#pragma unroll
    for (int mt = 0; mt < 4; mt++)
#pragma unroll
      for (int rg = 0; rg < 4; rg++) {
        int row = r0 + wm * 64 + mt * 16 + quad * 4 + rg;
        int b_ = row >> 12, s = row & 4095;
        float val = acc[mt][nt][rg] + bj;
        if (part == 0) {
          // 0.125 * log2(e): scores become exp2-domain; applied in fp32 BEFORE bf16 quantization
          q[((size_t)((b_ * 4 + head) * Ss + s) << 6) + d] = f2bf(val * 0.18033688f);
        } else if (part == 1) {
          kk_[((size_t)((b_ * 4 + head) * Ss + s) << 6) + d] = f2bf(val);
        } else {
          // permuted-transposed V: vt[bh][d][chunk*64 + slot]
          int chunk = s >> 6, w6 = s & 63;
          int t = w6 >> 4, qq = (w6 >> 2) & 3, r = w6 & 3;
          int slot = ((t >> 1) << 5) | (qq << 3) | ((t & 1) << 2) | r;
          vt_[((size_t)((b_ * 4 + head) * 64 + d) << 12) + chunk * 64 + slot] = f2bf(val);
        }
      }
  }
}

// ---------------- kernel 2: flash attention, S^T formulation, exp2 no-max softmax ----------------
// 2 waves / 64 q-rows per block => grid 1024 (8 blocks/CU resident, LDS-capped) for barrier overlap.
__global__ __launch_bounds__(128) void k_attn(const u16* __restrict__ Q, const u16* __restrict__ K,
                                              const u16* __restrict__ VT, u16* __restrict__ AO) {
  __shared__ u16 Kl[64][72];
  __shared__ u16 Vl[64][72];
  const int tid = threadIdx.x;
  const int wv = tid >> 6, lane = tid & 63;
  const int lr = lane & 15, quad = lane >> 4;
  const int bh = blockIdx.y;
  const int b_ = bh >> 2, head = bh & 3;
  const int qbase = blockIdx.x * 64 + wv * 32;
  const u16* Qh = Q + (size_t)bh * Ss * HD;
  const u16* Kh = K + (size_t)bh * Ss * HD;
  const u16* Vh = VT + (size_t)bh * HD * Ss;  // [d][perm(s)]

  // Q as B-operand (pre-scaled in k_qkv): qb[nt][ks]
  bf16x8 qb[2][2];
#pragma unroll
  for (int nt = 0; nt < 2; nt++)
#pragma unroll
    for (int ks = 0; ks < 2; ks++)
      qb[nt][ks] = ldfrag(Qh + (size_t)(qbase + nt * 16 + lr) * HD + ks * 32 + quad * 8);

  f32x4 O[2][4] = {};
  float lsum[2] = {0.f, 0.f};

  for (int kc = 0; kc < 64; kc++) {
    __syncthreads();
#pragma unroll
    for (int e = 0; e < 4; e++) {
      int ss = tid + e * 128;
      int row = ss >> 3, seg = ss & 7;
      *(u16x8*)&Kl[row][seg * 8] = *(const u16x8*)(Kh + ((size_t)(kc * 64 + row) << 6) + seg * 8);
      *(u16x8*)&Vl[row][seg * 8] = *(const u16x8*)(Vh + ((size_t)row << 12) + kc * 64 + seg * 8);
    }
    __syncthreads();

    // S^T[key][q] = K·Q^T ; St[kt][nt]: lane holds key=kt*16+quad*4+rg, q=nt*16+lr
    f32x4 St[4][2] = {};
#pragma unroll
    for (int ks = 0; ks < 2; ks++) {
      bf16x8 ka[4];
#pragma unroll
      for (int kt = 0; kt < 4; kt++) ka[kt] = ldfrag(&Kl[kt * 16 + lr][ks * 32 + quad * 8]);
#pragma unroll
      for (int kt = 0; kt < 4; kt++)
#pragma unroll
        for (int nt = 0; nt < 2; nt++)
          St[kt][nt] = __builtin_amdgcn_mfma_f32_16x16x32_bf16(ka[kt], qb[nt][ks], St[kt][nt], 0, 0, 0);
    }

    // p = exp2(score') (score pre-scaled by log2e); per-lane l partials; pack bf16 in-register
    uint32_t pk[4][2][2];
#pragma unroll
    for (int kt = 0; kt < 4; kt++)
#pragma unroll
      for (int nt = 0; nt < 2; nt++) {
        float p0 = __builtin_amdgcn_exp2f(St[kt][nt][0]);
        float p1 = __builtin_amdgcn_exp2f(St[kt][nt][1]);
        float p2 = __builtin_amdgcn_exp2f(St[kt][nt][2]);
        float p3 = __builtin_amdgcn_exp2f(St[kt][nt][3]);
        lsum[nt] += (p0 + p1) + (p2 + p3);
        pk[kt][nt][0] = pack2bf(p0, p1);
        pk[kt][nt][1] = pack2bf(p2, p3);
      }

    // O += P·V : A-frag is the lane's own packed registers (key-permuted order matches VT layout)
#pragma unroll
    for (int ks = 0; ks < 2; ks++) {
      bf16x8 pa[2];
#pragma unroll
      for (int mt = 0; mt < 2; mt++) {
        u32x4 t = {pk[2 * ks][mt][0], pk[2 * ks][mt][1], pk[2 * ks + 1][mt][0], pk[2 * ks + 1][mt][1]};
        pa[mt] = __builtin_bit_cast(bf16x8, t);
      }
#pragma unroll
      for (int dt = 0; dt < 4; dt++) {
        bf16x8 vb = ldfrag(&Vl[dt * 16 + lr][ks * 32 + quad * 8]);
#pragma unroll
        for (int mt = 0; mt < 2; mt++)
          O[mt][dt] = __builtin_amdgcn_mfma_f32_16x16x32_bf16(pa[mt], vb, O[mt][dt], 0, 0, 0);
      }
    }
  }

  // finalize l across the 4 quads holding the same q-column
#pragma unroll
  for (int nt = 0; nt < 2; nt++) {
    lsum[nt] += __shfl_xor(lsum[nt], 16);
    lsum[nt] += __shfl_xor(lsum[nt], 32);
  }
#pragma unroll
  for (int mt = 0; mt < 2; mt++)
#pragma unroll
    for (int rg = 0; rg < 4; rg++) {
      float lv = __shfl(lsum[mt], quad * 4 + rg);
      float inv = 1.0f / lv;
      int s = qbase + mt * 16 + quad * 4 + rg;
#pragma unroll
      for (int dt = 0; dt < 4; dt++)
        AO[((size_t)(b_ * Ss + s) << 8) + head * 64 + dt * 16 + lr] = f2bf(O[mt][dt][rg] * inv);
    }
}

// ---------------- kernel 3: y^T = w_o * ao^T + b_o, stored as y[b][c][s] FP32 ----------------
__global__ __launch_bounds__(256) void k_oproj(const u16* __restrict__ wo, const u16* __restrict__ ao,
                                               const float* __restrict__ bo, float* __restrict__ y) {
  __shared__ u16 As[128][40], Bs[128][40];
  const int tid = threadIdx.x;
  const int wv = tid >> 6, lane = tid & 63;
  const int wm = wv >> 1, wn = wv & 1;
  const int lr = lane & 15, quad = lane >> 4;
  const int c0 = blockIdx.x * 128;
  const int n0 = blockIdx.y * 128;
  f32x4 acc[4][4] = {};
  for (int k0 = 0; k0 < 256; k0 += 32) {
    __syncthreads();
    stage_tile(wo, 256, c0, k0, As, tid);
    stage_tile(ao, 256, n0, k0, Bs, tid);
    __syncthreads();
    bf16x8 a[4], b[4];
#pragma unroll
    for (int mt = 0; mt < 4; mt++) a[mt] = ldfrag(&As[wm * 64 + mt * 16 + lr][quad * 8]);
#pragma unroll
    for (int nt = 0; nt < 4; nt++) b[nt] = ldfrag(&Bs[wn * 64 + nt * 16 + lr][quad * 8]);
#pragma unroll
    for (int mt = 0; mt < 4; mt++)
#pragma unroll
      for (int nt = 0; nt < 4; nt++)
        acc[mt][nt] = __builtin_amdgcn_mfma_f32_16x16x32_bf16(a[mt], b[nt], acc[mt][nt], 0, 0, 0);
  }
#pragma unroll
  for (int mt = 0; mt < 4; mt++)
#pragma unroll
    for (int rg = 0; rg < 4; rg++) {
      int c = c0 + wm * 64 + mt * 16 + quad * 4 + rg;
      float bc = bo[c];
#pragma unroll
      for (int nt = 0; nt < 4; nt++) {
        int col = n0 + wn * 64 + nt * 16 + lr;
        int b_ = col >> 12, s = col & 4095;
        y[((size_t)(b_ * Cc + c) << 12) + s] = acc[mt][nt][rg] + bc;
      }
    }
}

extern "C" void kernel_launch(void* const* d_in, const int* in_sizes, int n_in,
                              void* d_out, int out_size, void* d_ws, size_t ws_size,
                              hipStream_t stream) {
  const float* x = (const float*)d_in[0];
  const float* w_qkv = (const float*)d_in[1];
  const float* b_qkv = (const float*)d_in[2];
  const float* w_o = (const float*)d_in[3];
  const float* b_o = (const float*)d_in[4];
  float* y = (float*)d_out;
  u16* ws = (u16*)d_ws;
  u16* xt = ws;                        // [0, E) — reused as ao after k_qkv
  u16* q = ws + (size_t)ELEMS;         // [E, 2E)
  u16* k = ws + (size_t)2 * ELEMS;     // [2E, 3E)
  u16* vt = ws + (size_t)3 * ELEMS;    // [3E, 4E)  — transposed+permuted V
  u16* ao = xt;                        // alias: xt dead after k_qkv
  u16* wqb = ws + (size_t)4 * ELEMS;   // 196608
  u16* wob = wqb + 196608;             // 65536

  k_conv<<<768, 256, 0, stream>>>(w_qkv, wqb, 196608);
  k_conv<<<256, 256, 0, stream>>>(w_o, wob, 65536);
  k_transpose<<<dim3(64, 4, 4), 256, 0, stream>>>(x, xt);
  k_qkv<<<dim3(128, 6), 256, 0, stream>>>(xt, wqb, b_qkv, q, k, vt);
  k_attn<<<dim3(64, 16), 128, 0, stream>>>(q, k, vt, ao);
  k_oproj<<<dim3(2, 128), 256, 0, stream>>>(wob, ao, b_o, y);
}

// Round 6
// 251.217 us; speedup vs baseline: 1.2491x; 1.2491x over previous
//
#include <hip/hip_runtime.h>
#include <stdint.h>

#define DI __device__ __forceinline__

typedef __attribute__((ext_vector_type(8))) __bf16 bf16x8;
typedef __attribute__((ext_vector_type(8))) unsigned short u16x8;
typedef __attribute__((ext_vector_type(4))) float f32x4;
typedef __attribute__((ext_vector_type(4))) uint32_t u32x4;
typedef __attribute__((ext_vector_type(4))) unsigned short u16x4;
typedef unsigned short u16;

constexpr int Bb = 4, Cc = 256, Ss = 4096, HD = 64;
constexpr int ELEMS = Bb * Cc * Ss;  // 4194304

DI u16 f2bf(float f) {  // RNE
  union { float f; unsigned u; } x; x.f = f;
  return (u16)((x.u + 0x7FFFu + ((x.u >> 16) & 1u)) >> 16);
}
DI uint32_t pack2bf(float a, float b) {  // low16=bf(a), high16=bf(b)
  union { float f; uint32_t u; } xa, xb;
  xa.f = a; xb.f = b;
  return __builtin_amdgcn_perm(xb.u + 0x8000u, xa.u + 0x8000u, 0x07060302u);
}
DI bf16x8 ldfrag(const u16* p) { return __builtin_bit_cast(bf16x8, *(const u16x8*)p); }

// ---------------- fp32 -> bf16 convert ----------------
__global__ __launch_bounds__(256) void k_conv(const float* __restrict__ src, u16* __restrict__ dst, int n) {
  int i = blockIdx.x * 256 + threadIdx.x;
  if (i < n) dst[i] = f2bf(src[i]);
}

// ---------------- kernel 0: x (B,C,S) fp32 -> xt (B,S,C) bf16 ----------------
__global__ __launch_bounds__(256) void k_transpose(const float* __restrict__ x, u16* __restrict__ xt) {
  __shared__ u16 T[64][72];
  const int st = blockIdx.x, ct = blockIdx.y, b = blockIdx.z;
  const int tid = threadIdx.x;
#pragma unroll
  for (int e = 0; e < 2; e++) {
    int ss = tid + e * 256;
    int r = ss >> 3, seg = ss & 7;
    size_t base = ((size_t)(b * Cc + ct * 64 + r) << 12) + st * 64 + seg * 8;
    u16x8 t;
#pragma unroll
    for (int j = 0; j < 8; j++) t[j] = f2bf(x[base + j]);
    *(u16x8*)&T[r][seg * 8] = t;
  }
  __syncthreads();
#pragma unroll
  for (int e = 0; e < 2; e++) {
    int ss = tid + e * 256;
    int sr = ss >> 3, cseg = ss & 7;
    u16x8 o;
#pragma unroll
    for (int j = 0; j < 8; j++) o[j] = T[cseg * 8 + j][sr];
    *(u16x8*)(xt + ((size_t)(b * Ss + st * 64 + sr) << 8) + ct * 64 + cseg * 8) = o;
  }
}

// ---- shared GEMM staging: rows [r0,r0+128) x cols [k0,k0+32), pitch-40 LDS ----
DI void stage_tile(const u16* __restrict__ src, int pitch, int r0, int k0, u16 (*dst)[40], int tid) {
#pragma unroll
  for (int e = 0; e < 2; e++) {
    int c = tid + e * 256;
    int row = c >> 2, seg = c & 3;
    u16x8 t = *(const u16x8*)(src + (size_t)(r0 + row) * pitch + k0 + seg * 8);
    *(u16x8*)&dst[row][seg * 8] = t;
  }
}

// ---------------- kernel 1: qkv GEMM.  q:[bh][s][64]*(0.125*log2e)  k:[bh][s][64]  v:[bh][64][perm(s)] ----------------
__global__ __launch_bounds__(256) void k_qkv(const u16* __restrict__ xt, const u16* __restrict__ w,
                                             const float* __restrict__ bias,
                                             u16* __restrict__ q, u16* __restrict__ kk_, u16* __restrict__ vt_) {
  __shared__ u16 As[128][40], Bs[128][40];
  const int tid = threadIdx.x;
  const int wv = tid >> 6, lane = tid & 63;
  const int wm = wv >> 1, wn = wv & 1;
  const int lr = lane & 15, quad = lane >> 4;
  const int r0 = blockIdx.x * 128;
  const int j0 = blockIdx.y * 128;
  f32x4 acc[4][4] = {};
  for (int k0 = 0; k0 < 256; k0 += 32) {
    __syncthreads();
    stage_tile(xt, 256, r0, k0, As, tid);
    stage_tile(w, 256, j0, k0, Bs, tid);
    __syncthreads();
    bf16x8 a[4], b[4];
#pragma unroll
    for (int mt = 0; mt < 4; mt++) a[mt] = ldfrag(&As[wm * 64 + mt * 16 + lr][quad * 8]);
#pragma unroll
    for (int nt = 0; nt < 4; nt++) b[nt] = ldfrag(&Bs[wn * 64 + nt * 16 + lr][quad * 8]);
#pragma unroll
    for (int mt = 0; mt < 4; mt++)
#pragma unroll
      for (int nt = 0; nt < 4; nt++)
        acc[mt][nt] = __builtin_amdgcn_mfma_f32_16x16x32_bf16(a[mt], b[nt], acc[mt][nt], 0, 0, 0);
  }
#pragma unroll
  for (int nt = 0; nt < 4; nt++) {
    int j = j0 + wn * 64 + nt * 16 + lr;
    float bj = bias[j];
    int part = j >> 8, cc = j & 255, head = cc >> 6, d = cc & 63;
#pragma unroll
    for (int mt = 0; mt < 4; mt++)
#pragma unroll
      for (int rg = 0; rg < 4; rg++) {
        int row = r0 + wm * 64 + mt * 16 + quad * 4 + rg;
        int b_ = row >> 12, s = row & 4095;
        float val = acc[mt][nt][rg] + bj;
        if (part == 0) {
          // 0.125 * log2(e): exp2-domain scores; applied in fp32 BEFORE bf16 quantization
          q[((size_t)((b_ * 4 + head) * Ss + s) << 6) + d] = f2bf(val * 0.18033688f);
        } else if (part == 1) {
          kk_[((size_t)((b_ * 4 + head) * Ss + s) << 6) + d] = f2bf(val);
        } else {
          // permuted-transposed V: vt[bh][d][chunk*64 + slot]
          int chunk = s >> 6, w6 = s & 63;
          int t = w6 >> 4, qq = (w6 >> 2) & 3, r = w6 & 3;
          int slot = ((t >> 1) << 5) | (qq << 3) | ((t & 1) << 2) | r;
          vt_[((size_t)((b_ * 4 + head) * 64 + d) << 12) + chunk * 64 + slot] = f2bf(val);
        }
      }
  }
}

// ---------------- kernel 2: flash attention, S^T formulation, exp2 no-max softmax, K-split ----------------
// 4 waves / 128 q-rows per block; blockIdx.z = key-split index (nsplit blocks cover disjoint key ranges).
// nsplit==1: normalize + write bf16 ao.  nsplit==2: write unnormalized fp32 O + l partials (linear softmax).
__global__ __launch_bounds__(256) void k_attn(const u16* __restrict__ Q, const u16* __restrict__ K,
                                              const u16* __restrict__ VT, u16* __restrict__ AO,
                                              float* __restrict__ Opart, float* __restrict__ lpart,
                                              int nsplit) {
  __shared__ u16 Kl[64][72];
  __shared__ u16 Vl[64][72];
  const int tid = threadIdx.x;
  const int wv = tid >> 6, lane = tid & 63;
  const int lr = lane & 15, quad = lane >> 4;
  const int bh = blockIdx.y;
  const int b_ = bh >> 2, head = bh & 3;
  const int qbase = blockIdx.x * 128 + wv * 32;
  const int sp = blockIdx.z;
  const u16* Qh = Q + (size_t)bh * Ss * HD;
  const u16* Kh = K + (size_t)bh * Ss * HD;
  const u16* Vh = VT + (size_t)bh * HD * Ss;  // [d][perm(s)]

  // Q as B-operand (pre-scaled in k_qkv): qb[nt][ks]
  bf16x8 qb[2][2];
#pragma unroll
  for (int nt = 0; nt < 2; nt++)
#pragma unroll
    for (int ks = 0; ks < 2; ks++)
      qb[nt][ks] = ldfrag(Qh + (size_t)(qbase + nt * 16 + lr) * HD + ks * 32 + quad * 8);

  f32x4 O[2][4] = {};
  float lsum[2] = {0.f, 0.f};

  const int kc0 = sp * (64 / nsplit), kc1 = kc0 + (64 / nsplit);
  for (int kc = kc0; kc < kc1; kc++) {
    __syncthreads();
#pragma unroll
    for (int e = 0; e < 2; e++) {
      int ss = tid + e * 256;
      int row = ss >> 3, seg = ss & 7;
      *(u16x8*)&Kl[row][seg * 8] = *(const u16x8*)(Kh + ((size_t)(kc * 64 + row) << 6) + seg * 8);
      *(u16x8*)&Vl[row][seg * 8] = *(const u16x8*)(Vh + ((size_t)row << 12) + kc * 64 + seg * 8);
    }
    __syncthreads();

    // S^T[key][q] = K·Q^T ; St[kt][nt]: lane holds key=kt*16+quad*4+rg, q=nt*16+lr
    f32x4 St[4][2] = {};
#pragma unroll
    for (int ks = 0; ks < 2; ks++) {
      bf16x8 ka[4];
#pragma unroll
      for (int kt = 0; kt < 4; kt++) ka[kt] = ldfrag(&Kl[kt * 16 + lr][ks * 32 + quad * 8]);
#pragma unroll
      for (int kt = 0; kt < 4; kt++)
#pragma unroll
        for (int nt = 0; nt < 2; nt++)
          St[kt][nt] = __builtin_amdgcn_mfma_f32_16x16x32_bf16(ka[kt], qb[nt][ks], St[kt][nt], 0, 0, 0);
    }

    // p = exp2(score'); per-lane l partials; pack bf16 in-register
    uint32_t pk[4][2][2];
#pragma unroll
    for (int kt = 0; kt < 4; kt++)
#pragma unroll
      for (int nt = 0; nt < 2; nt++) {
        float p0 = __builtin_amdgcn_exp2f(St[kt][nt][0]);
        float p1 = __builtin_amdgcn_exp2f(St[kt][nt][1]);
        float p2 = __builtin_amdgcn_exp2f(St[kt][nt][2]);
        float p3 = __builtin_amdgcn_exp2f(St[kt][nt][3]);
        lsum[nt] += (p0 + p1) + (p2 + p3);
        pk[kt][nt][0] = pack2bf(p0, p1);
        pk[kt][nt][1] = pack2bf(p2, p3);
      }

    // O += P·V : A-frag is the lane's own packed registers (key-permuted order matches VT layout)
#pragma unroll
    for (int ks = 0; ks < 2; ks++) {
      bf16x8 pa[2];
#pragma unroll
      for (int mt = 0; mt < 2; mt++) {
        u32x4 t = {pk[2 * ks][mt][0], pk[2 * ks][mt][1], pk[2 * ks + 1][mt][0], pk[2 * ks + 1][mt][1]};
        pa[mt] = __builtin_bit_cast(bf16x8, t);
      }
#pragma unroll
      for (int dt = 0; dt < 4; dt++) {
        bf16x8 vb = ldfrag(&Vl[dt * 16 + lr][ks * 32 + quad * 8]);
#pragma unroll
        for (int mt = 0; mt < 2; mt++)
          O[mt][dt] = __builtin_amdgcn_mfma_f32_16x16x32_bf16(pa[mt], vb, O[mt][dt], 0, 0, 0);
      }
    }
  }

  // l: reduce across the 4 quads holding the same q-column -> every lane has its column total
#pragma unroll
  for (int nt = 0; nt < 2; nt++) {
    lsum[nt] += __shfl_xor(lsum[nt], 16);
    lsum[nt] += __shfl_xor(lsum[nt], 32);
  }

  if (nsplit == 1) {
#pragma unroll
    for (int mt = 0; mt < 2; mt++)
#pragma unroll
      for (int rg = 0; rg < 4; rg++) {
        float lv = __shfl(lsum[mt], quad * 4 + rg);
        float inv = 1.0f / lv;
        int s = qbase + mt * 16 + quad * 4 + rg;
#pragma unroll
        for (int dt = 0; dt < 4; dt++)
          AO[((size_t)(b_ * Ss + s) << 8) + head * 64 + dt * 16 + lr] = f2bf(O[mt][dt][rg] * inv);
      }
  } else {
    float* Op = Opart + (size_t)sp * ELEMS;
    float* lp = lpart + (size_t)sp * (16 * Ss) + bh * Ss;
    if (quad == 0) {
#pragma unroll
      for (int nt = 0; nt < 2; nt++) lp[qbase + nt * 16 + lr] = lsum[nt];
    }
#pragma unroll
    for (int mt = 0; mt < 2; mt++)
#pragma unroll
      for (int rg = 0; rg < 4; rg++) {
        int s = qbase + mt * 16 + quad * 4 + rg;
#pragma unroll
        for (int dt = 0; dt < 4; dt++)
          Op[((size_t)(b_ * Ss + s) << 8) + head * 64 + dt * 16 + lr] = O[mt][dt][rg];
      }
  }
}

// ---------------- combine split partials: ao = (O0+O1)/(l0+l1), bf16 ----------------
__global__ __launch_bounds__(256) void k_comb(const float* __restrict__ Opart, const float* __restrict__ lpart,
                                              u16* __restrict__ ao) {
  int idx = (blockIdx.x * 256 + threadIdx.x) * 4;  // over ELEMS, float4 per thread
  f32x4 o0 = *(const f32x4*)(Opart + idx);
  f32x4 o1 = *(const f32x4*)(Opart + (size_t)ELEMS + idx);
  int c = idx & 255, bs = idx >> 8;
  int b = bs >> 12, s = bs & 4095, head = c >> 6;
  int li = (b * 4 + head) * Ss + s;
  float l = lpart[li] + lpart[16 * Ss + li];
  float inv = 1.0f / l;
  u16x4 o;
#pragma unroll
  for (int j = 0; j < 4; j++) o[j] = f2bf((o0[j] + o1[j]) * inv);
  *(u16x4*)(ao + idx) = o;
}

// ---------------- kernel 3: y^T = w_o * ao^T + b_o, stored as y[b][c][s] FP32 ----------------
__global__ __launch_bounds__(256) void k_oproj(const u16* __restrict__ wo, const u16* __restrict__ ao,
                                               const float* __restrict__ bo, float* __restrict__ y) {
  __shared__ u16 As[128][40], Bs[128][40];
  const int tid = threadIdx.x;
  const int wv = tid >> 6, lane = tid & 63;
  const int wm = wv >> 1, wn = wv & 1;
  const int lr = lane & 15, quad = lane >> 4;
  const int c0 = blockIdx.x * 128;
  const int n0 = blockIdx.y * 128;
  f32x4 acc[4][4] = {};
  for (int k0 = 0; k0 < 256; k0 += 32) {
    __syncthreads();
    stage_tile(wo, 256, c0, k0, As, tid);
    stage_tile(ao, 256, n0, k0, Bs, tid);
    __syncthreads();
    bf16x8 a[4], b[4];
#pragma unroll
    for (int mt = 0; mt < 4; mt++) a[mt] = ldfrag(&As[wm * 64 + mt * 16 + lr][quad * 8]);
#pragma unroll
    for (int nt = 0; nt < 4; nt++) b[nt] = ldfrag(&Bs[wn * 64 + nt * 16 + lr][quad * 8]);
#pragma unroll
    for (int mt = 0; mt < 4; mt++)
#pragma unroll
      for (int nt = 0; nt < 4; nt++)
        acc[mt][nt] = __builtin_amdgcn_mfma_f32_16x16x32_bf16(a[mt], b[nt], acc[mt][nt], 0, 0, 0);
  }
#pragma unroll
  for (int mt = 0; mt < 4; mt++)
#pragma unroll
    for (int rg = 0; rg < 4; rg++) {
      int c = c0 + wm * 64 + mt * 16 + quad * 4 + rg;
      float bc = bo[c];
#pragma unroll
      for (int nt = 0; nt < 4; nt++) {
        int col = n0 + wn * 64 + nt * 16 + lr;
        int b_ = col >> 12, s = col & 4095;
        y[((size_t)(b_ * Cc + c) << 12) + s] = acc[mt][nt][rg] + bc;
      }
    }
}

extern "C" void kernel_launch(void* const* d_in, const int* in_sizes, int n_in,
                              void* d_out, int out_size, void* d_ws, size_t ws_size,
                              hipStream_t stream) {
  const float* x = (const float*)d_in[0];
  const float* w_qkv = (const float*)d_in[1];
  const float* b_qkv = (const float*)d_in[2];
  const float* w_o = (const float*)d_in[3];
  const float* b_o = (const float*)d_in[4];
  float* y = (float*)d_out;
  u16* ws = (u16*)d_ws;
  u16* xt = ws;                        // [0, E) — reused as ao after k_qkv
  u16* q = ws + (size_t)ELEMS;         // [E, 2E)
  u16* k = ws + (size_t)2 * ELEMS;     // [2E, 3E)
  u16* vt = ws + (size_t)3 * ELEMS;    // [3E, 4E)  — transposed+permuted V
  u16* ao = xt;                        // alias: xt dead after k_qkv
  u16* wqb = ws + (size_t)4 * ELEMS;   // 196608
  u16* wob = wqb + 196608;             // 65536
  // fp32 partials (K-split path): after weights, 4-byte aligned (offset is even u16 count)
  float* Opart = (float*)(wob + 65536);            // 2*ELEMS floats = 33.5 MB
  float* lpart = Opart + (size_t)2 * ELEMS;        // 2*16*4096 floats
  const size_t need = ((size_t)4 * ELEMS + 262144) * 2 + (size_t)2 * ELEMS * 4 + (size_t)2 * 16 * Ss * 4;
  const int nsplit = (ws_size >= need) ? 2 : 1;

  k_conv<<<768, 256, 0, stream>>>(w_qkv, wqb, 196608);
  k_conv<<<256, 256, 0, stream>>>(w_o, wob, 65536);
  k_transpose<<<dim3(64, 4, 4), 256, 0, stream>>>(x, xt);
  k_qkv<<<dim3(128, 6), 256, 0, stream>>>(xt, wqb, b_qkv, q, k, vt);
  k_attn<<<dim3(32, 16, nsplit), 256, 0, stream>>>(q, k, vt, ao, Opart, lpart, nsplit);
  if (nsplit == 2) k_comb<<<ELEMS / 1024, 256, 0, stream>>>(Opart, lpart, ao);
  k_oproj<<<dim3(2, 128), 256, 0, stream>>>(wob, ao, b_o, y);
}

// Round 7
// 190.598 us; speedup vs baseline: 1.6463x; 1.3180x over previous
//
#include <hip/hip_runtime.h>
#include <stdint.h>

#define DI __device__ __forceinline__

typedef __attribute__((ext_vector_type(8))) __bf16 bf16x8;
typedef __attribute__((ext_vector_type(8))) unsigned short u16x8;
typedef __attribute__((ext_vector_type(4))) float f32x4;
typedef __attribute__((ext_vector_type(4))) uint32_t u32x4;
typedef __attribute__((ext_vector_type(4))) unsigned short u16x4;
typedef unsigned short u16;

constexpr int Bb = 4, Cc = 256, Ss = 4096, HD = 64;
constexpr int ELEMS = Bb * Cc * Ss;  // 4194304

DI u16 f2bf(float f) {
  union { float f; unsigned u; } x; x.f = f;
  return (u16)((x.u + 0x7FFFu + ((x.u >> 16) & 1u)) >> 16);
}
DI uint32_t pack2bf(float a, float b) {  // low16=bf(a), high16=bf(b)
  union { float f; uint32_t u; } xa, xb;
  xa.f = a; xb.f = b;
  return __builtin_amdgcn_perm(xb.u + 0x8000u, xa.u + 0x8000u, 0x07060302u);
}
DI bf16x8 ldfrag(const u16* p) { return __builtin_bit_cast(bf16x8, *(const u16x8*)p); }

// ---------------- fp32 -> bf16 convert, both weight matrices in one launch ----------------
__global__ __launch_bounds__(256) void k_convw(const float* __restrict__ w1, const float* __restrict__ w2,
                                               u16* __restrict__ d1, u16* __restrict__ d2) {
  int i = blockIdx.x * 256 + threadIdx.x;
  if (i < 196608) d1[i] = f2bf(w1[i]);
  if (i < 65536) d2[i] = f2bf(w2[i]);
}

// ---------------- kernel 0: x (B,C,S) fp32 -> xt (B,S,C) bf16 ----------------
__global__ __launch_bounds__(256) void k_transpose(const float* __restrict__ x, u16* __restrict__ xt) {
  __shared__ u16 T[64][72];
  const int st = blockIdx.x, ct = blockIdx.y, b = blockIdx.z;
  const int tid = threadIdx.x;
#pragma unroll
  for (int e = 0; e < 2; e++) {
    int ss = tid + e * 256;
    int r = ss >> 3, seg = ss & 7;
    size_t base = ((size_t)(b * Cc + ct * 64 + r) << 12) + st * 64 + seg * 8;
    u16x8 t;
#pragma unroll
    for (int j = 0; j < 8; j++) t[j] = f2bf(x[base + j]);
    *(u16x8*)&T[r][seg * 8] = t;
  }
  __syncthreads();
#pragma unroll
  for (int e = 0; e < 2; e++) {
    int ss = tid + e * 256;
    int sr = ss >> 3, cseg = ss & 7;
    u16x8 o;
#pragma unroll
    for (int j = 0; j < 8; j++) o[j] = T[cseg * 8 + j][sr];
    *(u16x8*)(xt + ((size_t)(b * Ss + st * 64 + sr) << 8) + ct * 64 + cseg * 8) = o;
  }
}

// ---- shared GEMM staging: rows [r0,r0+128) x cols [k0,k0+32), pitch-40 LDS ----
DI void stage_tile(const u16* __restrict__ src, int pitch, int r0, int k0, u16 (*dst)[40], int tid) {
#pragma unroll
  for (int e = 0; e < 2; e++) {
    int c = tid + e * 256;
    int row = c >> 2, seg = c & 3;
    u16x8 t = *(const u16x8*)(src + (size_t)(r0 + row) * pitch + k0 + seg * 8);
    *(u16x8*)&dst[row][seg * 8] = t;
  }
}

// ---------------- kernel 1: qkv GEMM.  q:[bh][s][64]*(0.125*log2e)  k:[bh][s][64]  v:[bh][64][perm(s)] ----------------
__global__ __launch_bounds__(256) void k_qkv(const u16* __restrict__ xt, const u16* __restrict__ w,
                                             const float* __restrict__ bias,
                                             u16* __restrict__ q, u16* __restrict__ kk_, u16* __restrict__ vt_) {
  __shared__ u16 As[128][40], Bs[128][40];
  const int tid = threadIdx.x;
  const int wv = tid >> 6, lane = tid & 63;
  const int wm = wv >> 1, wn = wv & 1;
  const int lr = lane & 15, quad = lane >> 4;
  const int r0 = blockIdx.x * 128;
  const int j0 = blockIdx.y * 128;
  f32x4 acc[4][4] = {};
  for (int k0 = 0; k0 < 256; k0 += 32) {
    __syncthreads();
    stage_tile(xt, 256, r0, k0, As, tid);
    stage_tile(w, 256, j0, k0, Bs, tid);
    __syncthreads();
    bf16x8 a[4], b[4];
#pragma unroll
    for (int mt = 0; mt < 4; mt++) a[mt] = ldfrag(&As[wm * 64 + mt * 16 + lr][quad * 8]);
#pragma unroll
    for (int nt = 0; nt < 4; nt++) b[nt] = ldfrag(&Bs[wn * 64 + nt * 16 + lr][quad * 8]);
#pragma unroll
    for (int mt = 0; mt < 4; mt++)
#pragma unroll
      for (int nt = 0; nt < 4; nt++)
        acc[mt][nt] = __builtin_amdgcn_mfma_f32_16x16x32_bf16(a[mt], b[nt], acc[mt][nt], 0, 0, 0);
  }
#pragma unroll
  for (int nt = 0; nt < 4; nt++) {
    int j = j0 + wn * 64 + nt * 16 + lr;
    float bj = bias[j];
    int part = j >> 8, cc = j & 255, head = cc >> 6, d = cc & 63;
#pragma unroll
    for (int mt = 0; mt < 4; mt++)
#pragma unroll
      for (int rg = 0; rg < 4; rg++) {
        int row = r0 + wm * 64 + mt * 16 + quad * 4 + rg;
        int b_ = row >> 12, s = row & 4095;
        float val = acc[mt][nt][rg] + bj;
        if (part == 0) {
          q[((size_t)((b_ * 4 + head) * Ss + s) << 6) + d] = f2bf(val * 0.18033688f);
        } else if (part == 1) {
          kk_[((size_t)((b_ * 4 + head) * Ss + s) << 6) + d] = f2bf(val);
        } else {
          int chunk = s >> 6, w6 = s & 63;
          int t = w6 >> 4, qq = (w6 >> 2) & 3, r = w6 & 3;
          int slot = ((t >> 1) << 5) | (qq << 3) | ((t & 1) << 2) | r;
          vt_[((size_t)((b_ * 4 + head) * 64 + d) << 12) + chunk * 64 + slot] = f2bf(val);
        }
      }
  }
}

// ---------------- kernel 2: flash attention, S^T form, exp2 no-max softmax ----------------
// 64 queries/wave, 256 q-rows/block (4 waves), double-buffered K/V staging, 1 barrier/chunk,
// K-split over blockIdx.z (linear softmax => partials add exactly).
__global__ __launch_bounds__(256, 2) void k_attn(const u16* __restrict__ Q, const u16* __restrict__ K,
                                                 const u16* __restrict__ VT, u16* __restrict__ AO,
                                                 float* __restrict__ Opart, float* __restrict__ lpart,
                                                 int nsplit) {
  __shared__ u16 Kl[2][64][72];
  __shared__ u16 Vl[2][64][72];
  const int tid = threadIdx.x;
  const int wv = tid >> 6, lane = tid & 63;
  const int lr = lane & 15, quad = lane >> 4;
  const int bh = blockIdx.y;
  const int b_ = bh >> 2, head = bh & 3;
  const int qbase = blockIdx.x * 256 + wv * 64;
  const int sp = blockIdx.z;
  const int nchunk = 64 / nsplit, kcg0 = sp * nchunk;
  const u16* Qh = Q + (size_t)bh * Ss * HD;
  const u16* Kh = K + (size_t)bh * Ss * HD;
  const u16* Vh = VT + (size_t)bh * HD * Ss;  // [d][perm(s)]

  // Q as B-operand (pre-scaled by 0.125*log2e in k_qkv): qb[nt][ks], 64 queries
  bf16x8 qb[4][2];
#pragma unroll
  for (int nt = 0; nt < 4; nt++)
#pragma unroll
    for (int ks = 0; ks < 2; ks++)
      qb[nt][ks] = ldfrag(Qh + (size_t)(qbase + nt * 16 + lr) * HD + ks * 32 + quad * 8);

  f32x4 O[4][4] = {};
  float lsum[4] = {0.f, 0.f, 0.f, 0.f};

  // staging prefetch registers: 32 B K + 32 B V per thread per chunk
  u16x8 pf[4];
  const int srow = tid >> 3, sseg = tid & 7;  // covers rows 0..31 (e=0) / 32..63 (e=1)
  auto load_chunk = [&](int kc) {
#pragma unroll
    for (int e = 0; e < 2; e++) {
      pf[e] = *(const u16x8*)(Kh + ((size_t)((kcg0 + kc) * 64 + srow + e * 32) << 6) + sseg * 8);
      pf[2 + e] = *(const u16x8*)(Vh + ((size_t)(srow + e * 32) << 12) + (kcg0 + kc) * 64 + sseg * 8);
    }
  };
  auto store_chunk = [&](int buf) {
#pragma unroll
    for (int e = 0; e < 2; e++) {
      *(u16x8*)&Kl[buf][srow + e * 32][sseg * 8] = pf[e];
      *(u16x8*)&Vl[buf][srow + e * 32][sseg * 8] = pf[2 + e];
    }
  };

  load_chunk(0);
  store_chunk(0);
  if (nchunk > 1) load_chunk(1);  // in flight across first compute
  __syncthreads();

  for (int kc = 0; kc < nchunk; kc++) {
    const int cur = kc & 1;
    // S^T[key][q] = K·Q^T ; St[kt][nt]: lane holds key=kt*16+quad*4+rg, q=nt*16+lr
    f32x4 St[4][4] = {};
#pragma unroll
    for (int ks = 0; ks < 2; ks++) {
      bf16x8 ka[4];
#pragma unroll
      for (int kt = 0; kt < 4; kt++) ka[kt] = ldfrag(&Kl[cur][kt * 16 + lr][ks * 32 + quad * 8]);
#pragma unroll
      for (int kt = 0; kt < 4; kt++)
#pragma unroll
        for (int nt = 0; nt < 4; nt++)
          St[kt][nt] = __builtin_amdgcn_mfma_f32_16x16x32_bf16(ka[kt], qb[nt][ks], St[kt][nt], 0, 0, 0);
    }

    // p = exp2(score'); per-lane l partials; pack bf16 pairs in-register
    uint32_t pk[4][4][2];
#pragma unroll
    for (int kt = 0; kt < 4; kt++)
#pragma unroll
      for (int nt = 0; nt < 4; nt++) {
        float p0 = __builtin_amdgcn_exp2f(St[kt][nt][0]);
        float p1 = __builtin_amdgcn_exp2f(St[kt][nt][1]);
        float p2 = __builtin_amdgcn_exp2f(St[kt][nt][2]);
        float p3 = __builtin_amdgcn_exp2f(St[kt][nt][3]);
        lsum[nt] += (p0 + p1) + (p2 + p3);
        pk[kt][nt][0] = pack2bf(p0, p1);
        pk[kt][nt][1] = pack2bf(p2, p3);
      }

    // O += P·V : A-frag is the lane's own packed registers (key-permuted order matches VT layout)
#pragma unroll
    for (int ks = 0; ks < 2; ks++) {
      bf16x8 pa[4];
#pragma unroll
      for (int mt = 0; mt < 4; mt++) {
        u32x4 t = {pk[2 * ks][mt][0], pk[2 * ks][mt][1], pk[2 * ks + 1][mt][0], pk[2 * ks + 1][mt][1]};
        pa[mt] = __builtin_bit_cast(bf16x8, t);
      }
#pragma unroll
      for (int dt = 0; dt < 4; dt++) {
        bf16x8 vb = ldfrag(&Vl[cur][dt * 16 + lr][ks * 32 + quad * 8]);
#pragma unroll
        for (int mt = 0; mt < 4; mt++)
          O[mt][dt] = __builtin_amdgcn_mfma_f32_16x16x32_bf16(pa[mt], vb, O[mt][dt], 0, 0, 0);
      }
    }

    // stage chunk kc+1 into the other buffer; issue loads for kc+2
    if (kc + 1 < nchunk) {
      store_chunk(cur ^ 1);
      if (kc + 2 < nchunk) load_chunk(kc + 2);
    }
    __syncthreads();
  }

  // l: reduce across the 4 quads holding the same q-column -> every lane has its column total
#pragma unroll
  for (int nt = 0; nt < 4; nt++) {
    lsum[nt] += __shfl_xor(lsum[nt], 16);
    lsum[nt] += __shfl_xor(lsum[nt], 32);
  }

  if (nsplit == 1) {
#pragma unroll
    for (int mt = 0; mt < 4; mt++)
#pragma unroll
      for (int rg = 0; rg < 4; rg++) {
        float lv = __shfl(lsum[mt], quad * 4 + rg + (lane & 48));
        // note: need l of column q = mt*16 + quad*4+rg within same 16-lane group
        lv = __shfl(lsum[mt], quad * 4 + rg);
        float inv = 1.0f / lv;
        int s = qbase + mt * 16 + quad * 4 + rg;
#pragma unroll
        for (int dt = 0; dt < 4; dt++)
          AO[((size_t)(b_ * Ss + s) << 8) + head * 64 + dt * 16 + lr] = f2bf(O[mt][dt][rg] * inv);
      }
  } else {
    float* Op = Opart + (size_t)sp * ELEMS;
    float* lp = lpart + (size_t)sp * (16 * Ss) + bh * Ss;
    if (quad == 0) {
#pragma unroll
      for (int nt = 0; nt < 4; nt++) lp[qbase + nt * 16 + lr] = lsum[nt];
    }
#pragma unroll
    for (int mt = 0; mt < 4; mt++)
#pragma unroll
      for (int rg = 0; rg < 4; rg++) {
        int s = qbase + mt * 16 + quad * 4 + rg;
#pragma unroll
        for (int dt = 0; dt < 4; dt++)
          Op[((size_t)(b_ * Ss + s) << 8) + head * 64 + dt * 16 + lr] = O[mt][dt][rg];
      }
  }
}

// ---------------- combine split partials: ao = (O0+O1)/(l0+l1), bf16 ----------------
__global__ __launch_bounds__(256) void k_comb(const float* __restrict__ Opart, const float* __restrict__ lpart,
                                              u16* __restrict__ ao) {
  int idx = (blockIdx.x * 256 + threadIdx.x) * 4;
  f32x4 o0 = *(const f32x4*)(Opart + idx);
  f32x4 o1 = *(const f32x4*)(Opart + (size_t)ELEMS + idx);
  int c = idx & 255, bs = idx >> 8;
  int b = bs >> 12, s = bs & 4095, head = c >> 6;
  int li = (b * 4 + head) * Ss + s;
  float l = lpart[li] + lpart[16 * Ss + li];
  float inv = 1.0f / l;
  u16x4 o;
#pragma unroll
  for (int j = 0; j < 4; j++) o[j] = f2bf((o0[j] + o1[j]) * inv);
  *(u16x4*)(ao + idx) = o;
}

// ---------------- kernel 3: y^T = w_o * ao^T + b_o, stored as y[b][c][s] FP32 ----------------
__global__ __launch_bounds__(256) void k_oproj(const u16* __restrict__ wo, const u16* __restrict__ ao,
                                               const float* __restrict__ bo, float* __restrict__ y) {
  __shared__ u16 As[128][40], Bs[128][40];
  const int tid = threadIdx.x;
  const int wv = tid >> 6, lane = tid & 63;
  const int wm = wv >> 1, wn = wv & 1;
  const int lr = lane & 15, quad = lane >> 4;
  const int c0 = blockIdx.x * 128;
  const int n0 = blockIdx.y * 128;
  f32x4 acc[4][4] = {};
  for (int k0 = 0; k0 < 256; k0 += 32) {
    __syncthreads();
    stage_tile(wo, 256, c0, k0, As, tid);
    stage_tile(ao, 256, n0, k0, Bs, tid);
    __syncthreads();
    bf16x8 a[4], b[4];
#pragma unroll
    for (int mt = 0; mt < 4; mt++) a[mt] = ldfrag(&As[wm * 64 + mt * 16 + lr][quad * 8]);
#pragma unroll
    for (int nt = 0; nt < 4; nt++) b[nt] = ldfrag(&Bs[wn * 64 + nt * 16 + lr][quad * 8]);
#pragma unroll
    for (int mt = 0; mt < 4; mt++)
#pragma unroll
      for (int nt = 0; nt < 4; nt++)
        acc[mt][nt] = __builtin_amdgcn_mfma_f32_16x16x32_bf16(a[mt], b[nt], acc[mt][nt], 0, 0, 0);
  }
#pragma unroll
  for (int mt = 0; mt < 4; mt++)
#pragma unroll
    for (int rg = 0; rg < 4; rg++) {
      int c = c0 + wm * 64 + mt * 16 + quad * 4 + rg;
      float bc = bo[c];
#pragma unroll
      for (int nt = 0; nt < 4; nt++) {
        int col = n0 + wn * 64 + nt * 16 + lr;
        int b_ = col >> 12, s = col & 4095;
        y[((size_t)(b_ * Cc + c) << 12) + s] = acc[mt][nt][rg] + bc;
      }
    }
}

extern "C" void kernel_launch(void* const* d_in, const int* in_sizes, int n_in,
                              void* d_out, int out_size, void* d_ws, size_t ws_size,
                              hipStream_t stream) {
  const float* x = (const float*)d_in[0];
  const float* w_qkv = (const float*)d_in[1];
  const float* b_qkv = (const float*)d_in[2];
  const float* w_o = (const float*)d_in[3];
  const float* b_o = (const float*)d_in[4];
  float* y = (float*)d_out;
  u16* ws = (u16*)d_ws;
  u16* xt = ws;                        // [0, E) — reused as ao after k_qkv
  u16* q = ws + (size_t)ELEMS;         // [E, 2E)
  u16* k = ws + (size_t)2 * ELEMS;     // [2E, 3E)
  u16* vt = ws + (size_t)3 * ELEMS;    // [3E, 4E)
  u16* ao = xt;
  u16* wqb = ws + (size_t)4 * ELEMS;   // 196608
  u16* wob = wqb + 196608;             // 65536
  float* Opart = (float*)(wob + 65536);
  float* lpart = Opart + (size_t)2 * ELEMS;
  const size_t need = ((size_t)4 * ELEMS + 262144) * 2 + (size_t)2 * ELEMS * 4 + (size_t)2 * 16 * Ss * 4;
  const int nsplit = (ws_size >= need) ? 2 : 1;

  k_convw<<<768, 256, 0, stream>>>(w_qkv, w_o, wqb, wob);
  k_transpose<<<dim3(64, 4, 4), 256, 0, stream>>>(x, xt);
  k_qkv<<<dim3(128, 6), 256, 0, stream>>>(xt, wqb, b_qkv, q, k, vt);
  k_attn<<<dim3(16, 16, nsplit), 256, 0, stream>>>(q, k, vt, ao, Opart, lpart, nsplit);
  if (nsplit == 2) k_comb<<<ELEMS / 1024, 256, 0, stream>>>(Opart, lpart, ao);
  k_oproj<<<dim3(2, 128), 256, 0, stream>>>(wob, ao, b_o, y);
}